// Round 1
// baseline (474.730 us; speedup 1.0000x reference)
//
#include <hip/hip_runtime.h>

#define LOG2E 1.4426950408889634f

typedef __attribute__((ext_vector_type(8))) short short8;
typedef __attribute__((ext_vector_type(4))) float f32x4;
using u32 = unsigned int;
using u16 = unsigned short;
using u64 = unsigned long long;

// ---------------------------------------------------------------------------
// Kernel F1 (fused prep + h-GEMM), 2048 blocks x 256 threads, 8 blocks/CU:
//   blocks [0,1024):   h = x@W slice GEMM. block = (rb64 = bx&255, oq = bx>>8)
//                      -> 64 rows x 16 output cols. W-slice staged bf16 into
//                      16KB xor-swizzled LDS (conflict-free ds_read_b128).
//                      Writes h_t bf16 slice + s1part/s2part o-quarter partials.
//   blocks [1024,2048): adj -> transposed bitmask (HBM stream overlaps the
//                      GEMM blocks on the same CUs) + zero the k2 counters.
// ---------------------------------------------------------------------------
__global__ __launch_bounds__(256, 8) void fused_prep(
        const float* __restrict__ x, const int* __restrict__ adj,
        const float* __restrict__ W, const float* __restrict__ a,
        u16* __restrict__ h_t, u32* __restrict__ mask_t,
        float* __restrict__ s1part, float* __restrict__ s2part,
        int* __restrict__ cnt) {
    __shared__ u16 wq[16 * 512];           // 16 KB, xor-swizzled 16B chunks
    const int bx = blockIdx.x;
    const int tid = threadIdx.x;

    if (bx >= 1024) {                      // ---- mask path ----
        if (bx == 1024 && tid < 256) cnt[tid] = 0;
        const int wid = ((bx - 1024) << 2) + (tid >> 6);   // [0,4096)
        const int lane = tid & 63;
        for (int t = wid; t < 65536; t += 4096) {          // 16 iters
            const int r = t >> 4, c4 = t & 15;
            const int* base = adj + (size_t)r * 4096 + c4 * 256 + lane;
            int v0 = __builtin_nontemporal_load(base);
            int v1 = __builtin_nontemporal_load(base + 64);
            int v2 = __builtin_nontemporal_load(base + 128);
            int v3 = __builtin_nontemporal_load(base + 192);
            u64 b0 = __ballot(v0 > 0);
            u64 b1 = __ballot(v1 > 0);
            u64 b2 = __ballot(v2 > 0);
            u64 b3 = __ballot(v3 > 0);
            if (lane < 8) {
                u64 bv = (lane & 4) ? ((lane & 2) ? b3 : b2) : ((lane & 2) ? b1 : b0);
                u32 w = (u32)(bv >> ((lane & 1) << 5));
                mask_t[(size_t)(c4 * 8 + lane) * 4096 + r] = w;
            }
        }
        return;
    }

    // ---- k1 path ----
    const int wave = tid >> 6, lane = tid & 63;
    const int m = lane & 15, quad = lane >> 4;
    const int rb64 = bx & 255, oq = bx >> 8;

    {   // stage W slice -> wq bf16 (round-half-up), chunk c xor (n&7) swizzle
        const int n_l = tid & 15, kg = tid >> 4;           // 16 k-groups of 32
        const float* wsrc = W + (size_t)(kg * 32) * 64 + oq * 16 + n_l;
#pragma unroll
        for (int kk = 0; kk < 32; kk += 2) {
            u32 c0 = __float_as_uint(wsrc[(size_t)kk * 64]) + 0x8000u;
            u32 c1 = __float_as_uint(wsrc[(size_t)(kk + 1) * 64]) + 0x8000u;
            int k = kg * 32 + kk;
            int c = k >> 3;
            *(u32*)&wq[n_l * 512 + ((c ^ (n_l & 7)) << 3) + (k & 7)] =
                (c0 >> 16) | (c1 & 0xffff0000u);
        }
    }
    __syncthreads();

    const int row = rb64 * 64 + wave * 16 + m;             // [0,16384)
    const float* xb = x + (size_t)row * 512 + quad * 8;
    f32x4 acc = (f32x4){0.f, 0.f, 0.f, 0.f};
    float4 ax[2][2];
    ax[0][0] = *(const float4*)(xb);
    ax[0][1] = *(const float4*)(xb + 4);
    ax[1][0] = *(const float4*)(xb + 32);
    ax[1][1] = *(const float4*)(xb + 36);
#pragma unroll
    for (int s = 0; s < 16; s++) {                         // K=512 in 16 steps
        const int cur = s & 1;
        union { u32 u[4]; short8 v; } af;
        const float* a0 = (const float*)&ax[cur][0];
#pragma unroll
        for (int p = 0; p < 4; p++) {                      // bf16 round-half-up
            u32 lo = __float_as_uint(a0[2 * p]) + 0x8000u;
            u32 hi = __float_as_uint(a0[2 * p + 1]) + 0x8000u;
            af.u[p] = __builtin_amdgcn_perm(hi, lo, 0x07060302u);
        }
        const int c = s * 4 + quad;
        short8 bf = *(const short8*)&wq[m * 512 + ((c ^ (m & 7)) << 3)];
        acc = __builtin_amdgcn_mfma_f32_16x16x32_bf16(af.v, bf, acc, 0, 0, 0);
        if (s + 2 < 16) {                                  // prefetch dist-2
            ax[cur][0] = *(const float4*)(xb + (s + 2) * 32);
            ax[cur][1] = *(const float4*)(xb + (s + 2) * 32 + 4);
        }
    }

    // epilogue: s1/s2 o-quarter partials (pre-scaled by log2e), shuffle reduce
    const float a1v = a[oq * 16 + m], a2v = a[64 + oq * 16 + m];
    float s1r[4], s2r[4];
#pragma unroll
    for (int r = 0; r < 4; r++) { s1r[r] = acc[r] * a1v; s2r[r] = acc[r] * a2v; }
#pragma unroll
    for (int d = 1; d < 16; d <<= 1) {
#pragma unroll
        for (int r = 0; r < 4; r++) {
            s1r[r] += __shfl_xor(s1r[r], d);
            s2r[r] += __shfl_xor(s2r[r], d);
        }
    }
    if (m == 0) {
#pragma unroll
        for (int r = 0; r < 4; r++) {
            int rr = rb64 * 64 + wave * 16 + quad * 4 + r;
            s1part[oq * 16384 + rr] = s1r[r] * LOG2E;
            s2part[oq * 16384 + rr] = s2r[r] * LOG2E;
        }
    }
    // h^T bf16 slice (round-half-up). C/D: col = oq*16+m, row = quad*4+r
    const int bb = rb64 >> 6, rb6 = rb64 & 63;
    u32 b0 = __float_as_uint(acc[0]) + 0x8000u;
    u32 b1 = __float_as_uint(acc[1]) + 0x8000u;
    u32 b2 = __float_as_uint(acc[2]) + 0x8000u;
    u32 b3 = __float_as_uint(acc[3]) + 0x8000u;
    uint2 u;
    u.x = (b0 >> 16) | (b1 & 0xffff0000u);
    u.y = (b2 >> 16) | (b3 & 0xffff0000u);
    *(uint2*)(h_t + ((size_t)(bb * 64 + oq * 16 + m)) * 4096
              + rb6 * 64 + wave * 16 + quad * 4) = u;
}

// ---------------------------------------------------------------------------
// Kernel F2: fused masked-softmax-numerator GEMM + completion-counter finisher
// (fused k3). S=8 (2048 WGs = 8 WG/CU), partials stored bf16.
// ---------------------------------------------------------------------------
template <int NSTEP>
__global__ __launch_bounds__(256, 8) void k2_attn(const u16* __restrict__ h_t,
                                                  const u32* __restrict__ mask_t,
                                                  const float* __restrict__ s1part,
                                                  const float* __restrict__ s2part,
                                                  u16* __restrict__ part,
                                                  float* __restrict__ lp,
                                                  int* __restrict__ cnt,
                                                  float* __restrict__ out) {
    constexpr int JSEG = NSTEP * 32;
    constexpr int T = NSTEP / 2;           // 64-j tiles
    constexpr int NSEG = 128 / NSTEP;      // j-split count
    __shared__ u16 hB[2][64 * 64];         // double buffer, xor-swizzled
    __shared__ float s2l[JSEG];
    __shared__ int ticket;
    const int b = blockIdx.y, seg = blockIdx.z, rb = blockIdx.x;
    const int tid = threadIdx.x, wave = tid >> 6, lane = tid & 63;
    const int m = lane & 15, quad = lane >> 4;
    const int row = rb * 64 + wave * 16 + m;
    const int jstart = seg * JSEG;
    const int ri = b * 4096 + row;
    const float t1 = s1part[ri] + s1part[16384 + ri]
                   + s1part[32768 + ri] + s1part[49152 + ri];
    const u16* hsrc = h_t + (size_t)b * 64 * 4096 + jstart;
    const u32* mrow = mask_t + (size_t)(jstart >> 5) * 4096 + row;

    const float* s2b = s2part + b * 4096 + jstart;
    for (int t = tid; t < (JSEG >> 2); t += 256) {
        float4 v0 = ((const float4*)s2b)[t];
        float4 v1 = ((const float4*)(s2b + 16384))[t];
        float4 v2 = ((const float4*)(s2b + 32768))[t];
        float4 v3 = ((const float4*)(s2b + 49152))[t];
        float4 o;
        o.x = (v0.x + v1.x) + (v2.x + v3.x);
        o.y = (v0.y + v1.y) + (v2.y + v3.y);
        o.z = (v0.z + v1.z) + (v2.z + v3.z);
        o.w = (v0.w + v1.w) + (v2.w + v3.w);
        ((float4*)s2l)[t] = o;
    }

    f32x4 acc[4], accd;
#pragma unroll
    for (int ot = 0; ot < 4; ot++) acc[ot] = (f32x4){0.f, 0.f, 0.f, 0.f};
    accd = (f32x4){0.f, 0.f, 0.f, 0.f};

    u32 mw[4];
#pragma unroll
    for (int s = 0; s < 4; s++) mw[s] = mrow[(size_t)s * 4096];
    union { u32 u[4]; short8 v; } ones;
#pragma unroll
    for (int p = 0; p < 4; p++) ones.u[p] = 0x3F803F80u;   // bf16 1.0 pairs

    const int cj = tid & 7;                // 16B chunk column (8 j's)
    const int ow = tid >> 3;               // rows ow, ow+32
    uint4 pf[2];
    pf[0] = *(const uint4*)(hsrc + (size_t)ow * 4096 + (cj << 3));
    pf[1] = *(const uint4*)(hsrc + (size_t)(ow + 32) * 4096 + (cj << 3));
    *(uint4*)(hB[0] + (size_t)ow * 64 + ((cj ^ (ow & 7)) << 3)) = pf[0];
    *(uint4*)(hB[0] + (size_t)(ow + 32) * 64 + ((cj ^ ((ow + 32) & 7)) << 3)) = pf[1];
    __syncthreads();                       // tile 0 + s2l ready

    for (int jt = 0; jt < T; jt++) {
        const int cb = jt & 1;
        if (jt + 1 < T) {                  // global prefetch of next 64-j tile
            pf[0] = *(const uint4*)(hsrc + (size_t)ow * 4096 + (jt + 1) * 64 + (cj << 3));
            pf[1] = *(const uint4*)(hsrc + (size_t)(ow + 32) * 4096 + (jt + 1) * 64 + (cj << 3));
        }
#pragma unroll
        for (int ks = 0; ks < 2; ks++) {
            const int s = jt * 2 + ks;
            const u32 mws = mw[s & 3] >> (quad * 8);
            if (s + 4 < NSTEP) mw[(s + 4) & 3] = mrow[(size_t)(s + 4) * 4096];

            const float4 sa = *(const float4*)&s2l[s * 32 + quad * 8];
            const float4 sb = *(const float4*)&s2l[s * 32 + quad * 8 + 4];
            const float sv[8] = {sa.x, sa.y, sa.z, sa.w, sb.x, sb.y, sb.z, sb.w};
            union { u32 u[4]; short8 v; } af;
#pragma unroll
            for (int p = 0; p < 4; p++) {
                float t0 = t1 + sv[2 * p];
                float u0 = fmaxf(t0, 0.2f * t0);                     // leaky-relu (log2 dom)
                float w0 = __builtin_amdgcn_exp2f(u0);
                u32 m0 = (u32)(((int)(mws << (31 - 2 * p))) >> 31);
                u32 w0u = __float_as_uint(w0) & m0;
                float t2 = t1 + sv[2 * p + 1];
                float u2 = fmaxf(t2, 0.2f * t2);
                float w1 = __builtin_amdgcn_exp2f(u2);
                u32 m1 = (u32)(((int)(mws << (30 - 2 * p))) >> 31);
                u32 w1u = __float_as_uint(w1) & m1;
                af.u[p] = __builtin_amdgcn_perm(w1u, w0u, 0x07060302u);
            }
            const int jc = ks * 4 + quad;
#pragma unroll
            for (int ot = 0; ot < 4; ot++) {
                const int o = ot * 16 + m;
                short8 bfv = *(const short8*)(hB[cb] + (size_t)o * 64 + ((jc ^ (o & 7)) << 3));
                acc[ot] = __builtin_amdgcn_mfma_f32_16x16x32_bf16(af.v, bfv, acc[ot], 0, 0, 0);
            }
            accd = __builtin_amdgcn_mfma_f32_16x16x32_bf16(af.v, ones.v, accd, 0, 0, 0);
        }
        if (jt + 1 < T) {
            const int nb = cb ^ 1;
            *(uint4*)(hB[nb] + (size_t)ow * 64 + ((cj ^ (ow & 7)) << 3)) = pf[0];
            *(uint4*)(hB[nb] + (size_t)(ow + 32) * 64 + ((cj ^ ((ow + 32) & 7)) << 3)) = pf[1];
        }
        __syncthreads();
    }
    // partials stored bf16; C/D layout: col=lane&15, row=quad*4+reg
    u16* pb = part + (((size_t)(seg * 4 + b) * 4096) + rb * 64 + wave * 16) * 64;
#pragma unroll
    for (int ot = 0; ot < 4; ot++)
#pragma unroll
        for (int r = 0; r < 4; r++) {
            u32 v = __float_as_uint(acc[ot][r]) + 0x8000u;
            pb[(quad * 4 + r) * 64 + ot * 16 + m] = (u16)(v >> 16);
        }
    if (m == 0) {                          // accd cols all equal; rows quad*4+r
        float* lpb = lp + (size_t)(seg * 4 + b) * 4096 + rb * 64 + wave * 16 + quad * 4;
#pragma unroll
        for (int r = 0; r < 4; r++) lpb[r] = accd[r];
    }

    // ---- fused k3: last seg-WG per (b,rb) combines, normalizes, ELUs ----
    __threadfence();                       // release partial stores agent-wide
    __syncthreads();                       // all threads' stores fenced
    if (tid == 0)
        ticket = __hip_atomic_fetch_add(&cnt[(b << 6) | rb], 1,
                                        __ATOMIC_ACQ_REL, __HIP_MEMORY_SCOPE_AGENT);
    __syncthreads();                       // broadcast ticket
    if (ticket != NSEG - 1) return;
    __threadfence();                       // acquire other XCDs' partials

    const int row_l = tid >> 2;            // 64 rows
    const int oq = tid & 3;                // 16 o's each
    const int frow = rb * 64 + row_l;
    float l = 0.f;
    float po[16];
#pragma unroll
    for (int i = 0; i < 16; i++) po[i] = 0.f;
#pragma unroll
    for (int s = 0; s < NSEG; s++) {
        const u16* ps = part + (((size_t)(s * 4 + b) * 4096) + frow) * 64 + oq * 16;
        uint4 q0 = *(const uint4*)ps;
        uint4 q1 = *(const uint4*)(ps + 8);
        const u32 w0[4] = {q0.x, q0.y, q0.z, q0.w};
        const u32 w1[4] = {q1.x, q1.y, q1.z, q1.w};
#pragma unroll
        for (int i = 0; i < 4; i++) {
            po[2 * i]     += __uint_as_float(w0[i] << 16);
            po[2 * i + 1] += __uint_as_float(w0[i] & 0xffff0000u);
            po[8 + 2 * i]     += __uint_as_float(w1[i] << 16);
            po[8 + 2 * i + 1] += __uint_as_float(w1[i] & 0xffff0000u);
        }
        l += lp[(size_t)(s * 4 + b) * 4096 + frow];
    }
    const float rl = 1.f / l;
    float ov[16];
#pragma unroll
    for (int i = 0; i < 16; i++) {
        float p = po[i] * rl;
        ov[i] = p > 0.f ? p : __builtin_amdgcn_exp2f(p * LOG2E) - 1.f;
    }
    float* ob = out + ((size_t)(b * 4096 + frow)) * 64 + oq * 16;
#pragma unroll
    for (int i = 0; i < 4; i++)
        *(float4*)(ob + i * 4) = *(float4*)&ov[i * 4];
}

// ---------------------------------------------------------------------------
extern "C" void kernel_launch(void* const* d_in, const int* in_sizes, int n_in,
                              void* d_out, int out_size, void* d_ws, size_t ws_size,
                              hipStream_t stream) {
    const float* x  = (const float*)d_in[0];
    const int* adj  = (const int*)d_in[1];
    const float* W  = (const float*)d_in[2];
    const float* a  = (const float*)d_in[3];
    float* out = (float*)d_out;
    char* ws = (char*)d_ws;

    // workspace layout
    u16* h_t      = (u16*)ws;                          // 2 MB
    u32* maskt    = (u32*)(ws + (2 << 20));            // 2 MB
    float* s1part = (float*)(ws + (4 << 20));          // 256 KB (4 o-quarters)
    float* s2part = s1part + 4 * 16384;                // 256 KB
    size_t base = (4u << 20) + 2 * 262144;
    int S = 8;                                         // k2 j-split: 8 WG/CU
    while (S > 1 && base + (size_t)S * (65536 + 2097152) + 1024 > ws_size) S >>= 1;
    float* lp = (float*)(ws + base);                   // S*64 KB
    u16* part = (u16*)(ws + base + (size_t)S * 65536); // S*2 MB (bf16)
    int* cnt  = (int*)(ws + base + (size_t)S * (65536 + 2097152));  // 1 KB

    fused_prep<<<2048, 256, 0, stream>>>(x, adj, W, a, h_t, maskt, s1part, s2part, cnt);
    if (S == 8)
        k2_attn<16><<<dim3(64, 4, 8), 256, 0, stream>>>(h_t, maskt, s1part, s2part, part, lp, cnt, out);
    else if (S == 4)
        k2_attn<32><<<dim3(64, 4, 4), 256, 0, stream>>>(h_t, maskt, s1part, s2part, part, lp, cnt, out);
    else if (S == 2)
        k2_attn<64><<<dim3(64, 4, 2), 256, 0, stream>>>(h_t, maskt, s1part, s2part, part, lp, cnt, out);
    else
        k2_attn<128><<<dim3(64, 4, 1), 256, 0, stream>>>(h_t, maskt, s1part, s2part, part, lp, cnt, out);
}

// Round 2
// 163.668 us; speedup vs baseline: 2.9006x; 2.9006x over previous
//
#include <hip/hip_runtime.h>

#define LOG2E 1.4426950408889634f

typedef __attribute__((ext_vector_type(8))) short short8;
typedef __attribute__((ext_vector_type(4))) float f32x4;
using u32 = unsigned int;
using u16 = unsigned short;
using u64 = unsigned long long;

// ---------------------------------------------------------------------------
// Kernel F1 (fused prep + h-GEMM), 2048 blocks x 256 threads, 8 blocks/CU:
//   blocks [0,1024):   h = x@W slice GEMM. block = (rb64 = bx&255, oq = bx>>8)
//                      -> 64 rows x 16 output cols. W-slice staged bf16 into
//                      16KB xor-swizzled LDS (conflict-free ds_read_b128).
//                      Writes h_t bf16 slice + s1part/s2part o-quarter partials.
//   blocks [1024,2048): adj -> transposed bitmask (HBM stream overlaps the
//                      GEMM blocks on the same CUs).
// NO cross-block fences anywhere (r1 lesson: agent-scope threadfence =
// buffer_wbl2/buffer_inv per WG = serialized L2 writebacks, 8x regression).
// ---------------------------------------------------------------------------
__global__ __launch_bounds__(256, 8) void fused_prep(
        const float* __restrict__ x, const int* __restrict__ adj,
        const float* __restrict__ W, const float* __restrict__ a,
        u16* __restrict__ h_t, u32* __restrict__ mask_t,
        float* __restrict__ s1part, float* __restrict__ s2part) {
    __shared__ u16 wq[16 * 512];           // 16 KB, xor-swizzled 16B chunks
    const int bx = blockIdx.x;
    const int tid = threadIdx.x;

    if (bx >= 1024) {                      // ---- mask path ----
        const int wid = ((bx - 1024) << 2) + (tid >> 6);   // [0,4096)
        const int lane = tid & 63;
        for (int t = wid; t < 65536; t += 4096) {          // 16 iters
            const int r = t >> 4, c4 = t & 15;
            const int* base = adj + (size_t)r * 4096 + c4 * 256 + lane;
            int v0 = __builtin_nontemporal_load(base);
            int v1 = __builtin_nontemporal_load(base + 64);
            int v2 = __builtin_nontemporal_load(base + 128);
            int v3 = __builtin_nontemporal_load(base + 192);
            u64 b0 = __ballot(v0 > 0);
            u64 b1 = __ballot(v1 > 0);
            u64 b2 = __ballot(v2 > 0);
            u64 b3 = __ballot(v3 > 0);
            if (lane < 8) {
                u64 bv = (lane & 4) ? ((lane & 2) ? b3 : b2) : ((lane & 2) ? b1 : b0);
                u32 w = (u32)(bv >> ((lane & 1) << 5));
                mask_t[(size_t)(c4 * 8 + lane) * 4096 + r] = w;
            }
        }
        return;
    }

    // ---- k1 path ----
    const int wave = tid >> 6, lane = tid & 63;
    const int m = lane & 15, quad = lane >> 4;
    const int rb64 = bx & 255, oq = bx >> 8;

    {   // stage W slice -> wq bf16 (round-half-up), chunk c xor (n&7) swizzle
        const int n_l = tid & 15, kg = tid >> 4;           // 16 k-groups of 32
        const float* wsrc = W + (size_t)(kg * 32) * 64 + oq * 16 + n_l;
#pragma unroll
        for (int kk = 0; kk < 32; kk += 2) {
            u32 c0 = __float_as_uint(wsrc[(size_t)kk * 64]) + 0x8000u;
            u32 c1 = __float_as_uint(wsrc[(size_t)(kk + 1) * 64]) + 0x8000u;
            int k = kg * 32 + kk;
            int c = k >> 3;
            *(u32*)&wq[n_l * 512 + ((c ^ (n_l & 7)) << 3) + (k & 7)] =
                (c0 >> 16) | (c1 & 0xffff0000u);
        }
    }
    __syncthreads();

    const int row = rb64 * 64 + wave * 16 + m;             // [0,16384)
    const float* xb = x + (size_t)row * 512 + quad * 8;
    f32x4 acc = (f32x4){0.f, 0.f, 0.f, 0.f};
    float4 ax[2][2];
    ax[0][0] = *(const float4*)(xb);
    ax[0][1] = *(const float4*)(xb + 4);
    ax[1][0] = *(const float4*)(xb + 32);
    ax[1][1] = *(const float4*)(xb + 36);
#pragma unroll
    for (int s = 0; s < 16; s++) {                         // K=512 in 16 steps
        const int cur = s & 1;
        union { u32 u[4]; short8 v; } af;
        const float* a0 = (const float*)&ax[cur][0];
#pragma unroll
        for (int p = 0; p < 4; p++) {                      // bf16 round-half-up
            u32 lo = __float_as_uint(a0[2 * p]) + 0x8000u;
            u32 hi = __float_as_uint(a0[2 * p + 1]) + 0x8000u;
            af.u[p] = __builtin_amdgcn_perm(hi, lo, 0x07060302u);
        }
        const int c = s * 4 + quad;
        short8 bf = *(const short8*)&wq[m * 512 + ((c ^ (m & 7)) << 3)];
        acc = __builtin_amdgcn_mfma_f32_16x16x32_bf16(af.v, bf, acc, 0, 0, 0);
        if (s + 2 < 16) {                                  // prefetch dist-2
            ax[cur][0] = *(const float4*)(xb + (s + 2) * 32);
            ax[cur][1] = *(const float4*)(xb + (s + 2) * 32 + 4);
        }
    }

    // epilogue: s1/s2 o-quarter partials (pre-scaled by log2e), shuffle reduce
    const float a1v = a[oq * 16 + m], a2v = a[64 + oq * 16 + m];
    float s1r[4], s2r[4];
#pragma unroll
    for (int r = 0; r < 4; r++) { s1r[r] = acc[r] * a1v; s2r[r] = acc[r] * a2v; }
#pragma unroll
    for (int d = 1; d < 16; d <<= 1) {
#pragma unroll
        for (int r = 0; r < 4; r++) {
            s1r[r] += __shfl_xor(s1r[r], d);
            s2r[r] += __shfl_xor(s2r[r], d);
        }
    }
    if (m == 0) {
#pragma unroll
        for (int r = 0; r < 4; r++) {
            int rr = rb64 * 64 + wave * 16 + quad * 4 + r;
            s1part[oq * 16384 + rr] = s1r[r] * LOG2E;
            s2part[oq * 16384 + rr] = s2r[r] * LOG2E;
        }
    }
    // h^T bf16 slice (round-half-up). C/D: col = oq*16+m, row = quad*4+r
    const int bb = rb64 >> 6, rb6 = rb64 & 63;
    u32 b0 = __float_as_uint(acc[0]) + 0x8000u;
    u32 b1 = __float_as_uint(acc[1]) + 0x8000u;
    u32 b2 = __float_as_uint(acc[2]) + 0x8000u;
    u32 b3 = __float_as_uint(acc[3]) + 0x8000u;
    uint2 u;
    u.x = (b0 >> 16) | (b1 & 0xffff0000u);
    u.y = (b2 >> 16) | (b3 & 0xffff0000u);
    *(uint2*)(h_t + ((size_t)(bb * 64 + oq * 16 + m)) * 4096
              + rb6 * 64 + wave * 16 + quad * 4) = u;
}

// ---------------------------------------------------------------------------
// Kernel 2: fused masked-softmax-numerator GEMM (round-0 structure, no
// finisher / no fences). S=8 (2048 WGs = 8 WG/CU), partials stored bf16.
// Only delta vs round-0: t1 and s2l sum the 4 o-quarter partials.
// ---------------------------------------------------------------------------
template <int NSTEP>
__global__ __launch_bounds__(256, 8) void k2_attn(const u16* __restrict__ h_t,
                                                  const u32* __restrict__ mask_t,
                                                  const float* __restrict__ s1part,
                                                  const float* __restrict__ s2part,
                                                  u16* __restrict__ part,
                                                  float* __restrict__ lp) {
    constexpr int JSEG = NSTEP * 32;
    constexpr int T = NSTEP / 2;           // 64-j tiles
    __shared__ u16 hB[2][64 * 64];         // double buffer, xor-swizzled
    __shared__ float s2l[JSEG];
    const int b = blockIdx.y, seg = blockIdx.z, rb = blockIdx.x;
    const int tid = threadIdx.x, wave = tid >> 6, lane = tid & 63;
    const int m = lane & 15, quad = lane >> 4;
    const int row = rb * 64 + wave * 16 + m;
    const int jstart = seg * JSEG;
    const int ri = b * 4096 + row;
    const float t1 = (s1part[ri] + s1part[16384 + ri])
                   + (s1part[32768 + ri] + s1part[49152 + ri]);
    const u16* hsrc = h_t + (size_t)b * 64 * 4096 + jstart;
    const u32* mrow = mask_t + (size_t)(jstart >> 5) * 4096 + row;

    const float* s2b = s2part + b * 4096 + jstart;
    for (int t = tid; t < (JSEG >> 2); t += 256) {
        float4 v0 = ((const float4*)s2b)[t];
        float4 v1 = ((const float4*)(s2b + 16384))[t];
        float4 v2 = ((const float4*)(s2b + 32768))[t];
        float4 v3 = ((const float4*)(s2b + 49152))[t];
        float4 o;
        o.x = (v0.x + v1.x) + (v2.x + v3.x);
        o.y = (v0.y + v1.y) + (v2.y + v3.y);
        o.z = (v0.z + v1.z) + (v2.z + v3.z);
        o.w = (v0.w + v1.w) + (v2.w + v3.w);
        ((float4*)s2l)[t] = o;
    }

    f32x4 acc[4], accd;
#pragma unroll
    for (int ot = 0; ot < 4; ot++) acc[ot] = (f32x4){0.f, 0.f, 0.f, 0.f};
    accd = (f32x4){0.f, 0.f, 0.f, 0.f};

    u32 mw[4];
#pragma unroll
    for (int s = 0; s < 4; s++) mw[s] = mrow[(size_t)s * 4096];
    union { u32 u[4]; short8 v; } ones;
#pragma unroll
    for (int p = 0; p < 4; p++) ones.u[p] = 0x3F803F80u;   // bf16 1.0 pairs

    const int cj = tid & 7;                // 16B chunk column (8 j's)
    const int ow = tid >> 3;               // rows ow, ow+32
    uint4 pf[2];
    pf[0] = *(const uint4*)(hsrc + (size_t)ow * 4096 + (cj << 3));
    pf[1] = *(const uint4*)(hsrc + (size_t)(ow + 32) * 4096 + (cj << 3));
    *(uint4*)(hB[0] + (size_t)ow * 64 + ((cj ^ (ow & 7)) << 3)) = pf[0];
    *(uint4*)(hB[0] + (size_t)(ow + 32) * 64 + ((cj ^ ((ow + 32) & 7)) << 3)) = pf[1];
    __syncthreads();                       // tile 0 + s2l ready

    for (int jt = 0; jt < T; jt++) {
        const int cb = jt & 1;
        if (jt + 1 < T) {                  // global prefetch of next 64-j tile
            pf[0] = *(const uint4*)(hsrc + (size_t)ow * 4096 + (jt + 1) * 64 + (cj << 3));
            pf[1] = *(const uint4*)(hsrc + (size_t)(ow + 32) * 4096 + (jt + 1) * 64 + (cj << 3));
        }
#pragma unroll
        for (int ks = 0; ks < 2; ks++) {
            const int s = jt * 2 + ks;
            const u32 mws = mw[s & 3] >> (quad * 8);
            if (s + 4 < NSTEP) mw[(s + 4) & 3] = mrow[(size_t)(s + 4) * 4096];

            const float4 sa = *(const float4*)&s2l[s * 32 + quad * 8];
            const float4 sb = *(const float4*)&s2l[s * 32 + quad * 8 + 4];
            const float sv[8] = {sa.x, sa.y, sa.z, sa.w, sb.x, sb.y, sb.z, sb.w};
            union { u32 u[4]; short8 v; } af;
#pragma unroll
            for (int p = 0; p < 4; p++) {
                float t0 = t1 + sv[2 * p];
                float u0 = fmaxf(t0, 0.2f * t0);                     // leaky-relu (log2 dom)
                float w0 = __builtin_amdgcn_exp2f(u0);
                u32 m0 = (u32)(((int)(mws << (31 - 2 * p))) >> 31);  // bit -> all-ones/0
                u32 w0u = __float_as_uint(w0) & m0;                  // masked -> +0.0
                float t2 = t1 + sv[2 * p + 1];
                float u2 = fmaxf(t2, 0.2f * t2);
                float w1 = __builtin_amdgcn_exp2f(u2);
                u32 m1 = (u32)(((int)(mws << (30 - 2 * p))) >> 31);
                u32 w1u = __float_as_uint(w1) & m1;
                af.u[p] = __builtin_amdgcn_perm(w1u, w0u, 0x07060302u);  // bf16 truncate
            }
            const int jc = ks * 4 + quad;
#pragma unroll
            for (int ot = 0; ot < 4; ot++) {
                const int o = ot * 16 + m;
                short8 bfv = *(const short8*)(hB[cb] + (size_t)o * 64 + ((jc ^ (o & 7)) << 3));
                acc[ot] = __builtin_amdgcn_mfma_f32_16x16x32_bf16(af.v, bfv, acc[ot], 0, 0, 0);
            }
            accd = __builtin_amdgcn_mfma_f32_16x16x32_bf16(af.v, ones.v, accd, 0, 0, 0);
        }
        if (jt + 1 < T) {                  // stage next tile into the idle buffer
            const int nb = cb ^ 1;
            *(uint4*)(hB[nb] + (size_t)ow * 64 + ((cj ^ (ow & 7)) << 3)) = pf[0];
            *(uint4*)(hB[nb] + (size_t)(ow + 32) * 64 + ((cj ^ ((ow + 32) & 7)) << 3)) = pf[1];
        }
        __syncthreads();
    }
    // C/D layout: col=lane&15, row=quad*4+reg; partials stored bf16 (RNE-ish)
    u16* pb = part + (((size_t)(seg * 4 + b) * 4096) + rb * 64 + wave * 16) * 64;
#pragma unroll
    for (int ot = 0; ot < 4; ot++)
#pragma unroll
        for (int r = 0; r < 4; r++) {
            u32 v = __float_as_uint(acc[ot][r]) + 0x8000u;
            pb[(quad * 4 + r) * 64 + ot * 16 + m] = (u16)(v >> 16);
        }
    if (m == 0) {                          // accd cols all equal; rows quad*4+r
        float* lpb = lp + (size_t)(seg * 4 + b) * 4096 + rb * 64 + wave * 16 + quad * 4;
#pragma unroll
        for (int r = 0; r < 4; r++) lpb[r] = accd[r];
    }
}

// ---------------------------------------------------------------------------
// Kernel 3: combine j-split bf16 partials, normalize, elu.
// ---------------------------------------------------------------------------
template <int S>
__global__ __launch_bounds__(256) void k3_fin(const u16* __restrict__ part,
                                              const float* __restrict__ lp,
                                              float* __restrict__ out) {
    int idx = blockIdx.x * 256 + threadIdx.x;    // 262144 = 4*4096*16
    int o4 = (idx & 15) << 2;
    int bi = idx >> 4;
    uint2 pv[S];
    float lv[S];
#pragma unroll
    for (int s = 0; s < S; s++) {
        pv[s] = *(const uint2*)&part[((size_t)s * 16384 + bi) * 64 + o4];
        lv[s] = lp[(size_t)s * 16384 + bi];
    }
    float p0 = 0.f, p1 = 0.f, p2 = 0.f, p3 = 0.f, l = 0.f;
#pragma unroll
    for (int s = 0; s < S; s++) {
        p0 += __uint_as_float(pv[s].x << 16);
        p1 += __uint_as_float(pv[s].x & 0xffff0000u);
        p2 += __uint_as_float(pv[s].y << 16);
        p3 += __uint_as_float(pv[s].y & 0xffff0000u);
        l += lv[s];
    }
    float rl = 1.f / l;
    p0 *= rl; p1 *= rl; p2 *= rl; p3 *= rl;
    float4 o;
    o.x = p0 > 0.f ? p0 : __builtin_amdgcn_exp2f(p0 * LOG2E) - 1.f;
    o.y = p1 > 0.f ? p1 : __builtin_amdgcn_exp2f(p1 * LOG2E) - 1.f;
    o.z = p2 > 0.f ? p2 : __builtin_amdgcn_exp2f(p2 * LOG2E) - 1.f;
    o.w = p3 > 0.f ? p3 : __builtin_amdgcn_exp2f(p3 * LOG2E) - 1.f;
    *(float4*)&out[(size_t)bi * 64 + o4] = o;
}

// ---------------------------------------------------------------------------
extern "C" void kernel_launch(void* const* d_in, const int* in_sizes, int n_in,
                              void* d_out, int out_size, void* d_ws, size_t ws_size,
                              hipStream_t stream) {
    const float* x  = (const float*)d_in[0];
    const int* adj  = (const int*)d_in[1];
    const float* W  = (const float*)d_in[2];
    const float* a  = (const float*)d_in[3];
    float* out = (float*)d_out;
    char* ws = (char*)d_ws;

    // workspace layout
    u16* h_t      = (u16*)ws;                          // 2 MB
    u32* maskt    = (u32*)(ws + (2 << 20));            // 2 MB
    float* s1part = (float*)(ws + (4 << 20));          // 256 KB (4 o-quarters)
    float* s2part = s1part + 4 * 16384;                // 256 KB
    size_t base = (4u << 20) + 2 * 262144;
    int S = 8;                                         // k2 j-split: 8 WG/CU
    while (S > 1 && base + (size_t)S * (65536 + 2097152) > ws_size) S >>= 1;
    float* lp = (float*)(ws + base);                   // S*64 KB
    u16* part = (u16*)(ws + base + (size_t)S * 65536); // S*2 MB (bf16)

    fused_prep<<<2048, 256, 0, stream>>>(x, adj, W, a, h_t, maskt, s1part, s2part);
    if (S == 8)
        k2_attn<16><<<dim3(64, 4, 8), 256, 0, stream>>>(h_t, maskt, s1part, s2part, part, lp);
    else if (S == 4)
        k2_attn<32><<<dim3(64, 4, 4), 256, 0, stream>>>(h_t, maskt, s1part, s2part, part, lp);
    else if (S == 2)
        k2_attn<64><<<dim3(64, 4, 2), 256, 0, stream>>>(h_t, maskt, s1part, s2part, part, lp);
    else
        k2_attn<128><<<dim3(64, 4, 1), 256, 0, stream>>>(h_t, maskt, s1part, s2part, part, lp);
    if (S == 8)      k3_fin<8><<<1024, 256, 0, stream>>>(part, lp, out);
    else if (S == 4) k3_fin<4><<<1024, 256, 0, stream>>>(part, lp, out);
    else if (S == 2) k3_fin<2><<<1024, 256, 0, stream>>>(part, lp, out);
    else             k3_fin<1><<<1024, 256, 0, stream>>>(part, lp, out);
}